// Round 2
// baseline (1952.743 us; speedup 1.0000x reference)
//
#include <hip/hip_runtime.h>
#include <math.h>

#define NN 16384
#define EE 262144
#define HH 256

#define INV_SQRT_3f 0.57735026918962576f
#define INV_SQRT_Hf 0.0625f
#define INV_SQRT_2f 0.70710678118654752f
#define SSILU_SCALE 1.6666666666666667f

__device__ __forceinline__ float ssilu_f(float v) {
    return v * (1.0f / (1.0f + __expf(-v))) * SSILU_SCALE;
}

// ---------------- LayerNorm: one block (256 thr) per row ----------------
__global__ void __launch_bounds__(256) ln_kernel(const float* __restrict__ x,
                                                 const float* __restrict__ g,
                                                 const float* __restrict__ b,
                                                 float* __restrict__ out) {
    int n = blockIdx.x;
    int t = threadIdx.x;
    float v = x[(long)n * HH + t];
    float s = v, s2 = v * v;
    #pragma unroll
    for (int off = 32; off > 0; off >>= 1) {
        s  += __shfl_down(s, off);
        s2 += __shfl_down(s2, off);
    }
    __shared__ float red[8];
    int wave = t >> 6, lane = t & 63;
    if (lane == 0) { red[wave] = s; red[4 + wave] = s2; }
    __syncthreads();
    __shared__ float mr[2];
    if (t == 0) {
        float ts = red[0] + red[1] + red[2] + red[3];
        float ts2 = red[4] + red[5] + red[6] + red[7];
        float mean = ts * (1.0f / HH);
        float var = ts2 * (1.0f / HH) - mean * mean;
        mr[0] = mean;
        mr[1] = rsqrtf(var + 1e-5f);
    }
    __syncthreads();
    out[(long)n * HH + t] = (v - mr[0]) * mr[1] * g[t] + b[t];
}

// ---- Generic tiled fp32 GEMM: C(M,Nc) = A(M,K) @ W(K,ldW sub-block) [+bias][ssilu]
// Requires M%64==0, K%16==0, Nc%64==0. W element [k][n] read at W[k*ldW + n],
// C written at C[m*ldC + n] (pass pre-offset W/C pointers for column slices).
__global__ void __launch_bounds__(256) gemm_kernel(const float* __restrict__ A,
                                                   const float* __restrict__ W,
                                                   const float* __restrict__ bias,
                                                   float* __restrict__ C,
                                                   int M, int K, int Nc,
                                                   int ldW, int ldC, int act) {
    __shared__ float As[16][68];
    __shared__ float Ws[16][64];
    int tid = threadIdx.x;
    int bm = blockIdx.x * 64;
    int bn = blockIdx.y * 64;
    int tx = tid & 15, ty = tid >> 4;
    int am = tid >> 2;          // 0..63
    int ak = (tid & 3) * 4;     // 0,4,8,12
    int wn = tid & 63, wk0 = tid >> 6;

    float acc[4][4];
    #pragma unroll
    for (int i = 0; i < 4; i++)
        #pragma unroll
        for (int j = 0; j < 4; j++) acc[i][j] = 0.0f;

    for (int k0 = 0; k0 < K; k0 += 16) {
        float4 av = *(const float4*)(A + (long)(bm + am) * K + k0 + ak);
        As[ak + 0][am] = av.x;
        As[ak + 1][am] = av.y;
        As[ak + 2][am] = av.z;
        As[ak + 3][am] = av.w;
        #pragma unroll
        for (int i = 0; i < 4; i++) {
            int k = i * 4 + wk0;
            Ws[k][wn] = W[(long)(k0 + k) * ldW + bn + wn];
        }
        __syncthreads();
        #pragma unroll
        for (int kk = 0; kk < 16; kk++) {
            float4 a4 = *(const float4*)(&As[kk][ty * 4]);
            float4 b4 = *(const float4*)(&Ws[kk][tx * 4]);
            float a[4] = {a4.x, a4.y, a4.z, a4.w};
            float b[4] = {b4.x, b4.y, b4.z, b4.w};
            #pragma unroll
            for (int i = 0; i < 4; i++)
                #pragma unroll
                for (int j = 0; j < 4; j++) acc[i][j] += a[i] * b[j];
        }
        __syncthreads();
    }

    float bj[4] = {0.f, 0.f, 0.f, 0.f};
    if (bias) {
        #pragma unroll
        for (int j = 0; j < 4; j++) bj[j] = bias[bn + tx * 4 + j];
    }
    #pragma unroll
    for (int i = 0; i < 4; i++) {
        long row = bm + ty * 4 + i;
        float v[4];
        #pragma unroll
        for (int j = 0; j < 4; j++) {
            v[j] = acc[i][j] + bj[j];
            if (act) v[j] = ssilu_f(v[j]);
        }
        float4 o = make_float4(v[0], v[1], v[2], v[3]);
        *(float4*)(C + row * ldC + bn + tx * 4) = o;
    }
}

// ---------------- Edge kernel: fused rbf GEMM + gather + messages + scatter-add ----
#define EPB 16
__global__ void __launch_bounds__(256) edge_kernel(const float* __restrict__ rbf,
                                                   const float* __restrict__ W_rbf,
                                                   const float* __restrict__ b_rbf,
                                                   const float* __restrict__ xh,
                                                   const float* __restrict__ vec,
                                                   const float* __restrict__ ev,
                                                   const int* __restrict__ eidx,
                                                   float* __restrict__ dx,
                                                   float* __restrict__ dvec) {
    __shared__ float rbf_s[EPB][64];
    __shared__ int src_s[EPB], dst_s[EPB];
    __shared__ float ev_s[EPB][3];
    int t = threadIdx.x;
    long e0 = (long)blockIdx.x * EPB;
    #pragma unroll
    for (int i = 0; i < (EPB * 64) / 256; i++) {
        int idx = i * 256 + t;
        rbf_s[idx >> 6][idx & 63] = rbf[e0 * 64 + idx];
    }
    if (t < EPB) { src_s[t] = eidx[e0 + t]; dst_s[t] = eidx[EE + e0 + t]; }
    if (t < EPB * 3) { int e = t / 3, d = t % 3; ev_s[e][d] = ev[(e0 + e) * 3 + d]; }
    __syncthreads();

    float acc1[EPB], acc2[EPB], acc3[EPB];
    float bb1 = b_rbf[t], bb2 = b_rbf[256 + t], bb3 = b_rbf[512 + t];
    #pragma unroll
    for (int e = 0; e < EPB; e++) { acc1[e] = bb1; acc2[e] = bb2; acc3[e] = bb3; }

    for (int k = 0; k < 64; k++) {
        float w1 = W_rbf[k * 768 + t];
        float w2 = W_rbf[k * 768 + 256 + t];
        float w3 = W_rbf[k * 768 + 512 + t];
        #pragma unroll
        for (int e = 0; e < EPB; e++) {
            float r = rbf_s[e][k];
            acc1[e] += r * w1;
            acc2[e] += r * w2;
            acc3[e] += r * w3;
        }
    }

    for (int e = 0; e < EPB; e++) {
        int s = src_s[e], d_ = dst_s[e];
        const float* xr = xh + (long)s * 768;
        float m1 = acc1[e] * xr[t];
        float m2 = acc2[e] * xr[256 + t] * INV_SQRT_3f;
        float m3 = acc3[e] * xr[512 + t];
        atomicAdd(&dx[(long)d_ * 256 + t], m1);
        const float* vr = vec + (long)s * 768;
        float* dvr = dvec + (long)d_ * 768;
        #pragma unroll
        for (int d = 0; d < 3; d++) {
            float vm = (vr[d * 256 + t] * m2 + m3 * ev_s[e][d]) * INV_SQRT_Hf;
            atomicAdd(&dvr[d * 256 + t], vm);
        }
    }
}

// ---------------- vec_dot + vnorm + cat(x, vnorm) ----------------
// vec1/vec2 are (3N, 256) row-major slices of vp.
__global__ void __launch_bounds__(256) vdot_cat_kernel(const float* __restrict__ vec1,
                                                       const float* __restrict__ vec2,
                                                       const float* __restrict__ x1,
                                                       float* __restrict__ vdot,
                                                       float* __restrict__ cat) {
    int idx = blockIdx.x * 256 + threadIdx.x;
    int n = idx >> 8, h = idx & 255;
    float dsum = 0.f, s2 = 0.f;
    #pragma unroll
    for (int d = 0; d < 3; d++) {
        long r = (long)(n * 3 + d) * 256 + h;
        float a = vec1[r];
        float b = vec2[r];
        dsum += a * b;
        s2 += b * b;
    }
    vdot[idx] = dsum * INV_SQRT_Hf;
    cat[(long)n * 512 + h] = x1[idx];
    cat[(long)n * 512 + 256 + h] = sqrtf(s2 + 1e-8f);
}

// ---------------- x/vec update after xv MLP (IN-PLACE on x1 and vecacc) ----------
__global__ void __launch_bounds__(256) e4_kernel(float* __restrict__ x1,
                                                 float* __restrict__ vecacc,
                                                 const float* __restrict__ vec1,
                                                 const float* __restrict__ vdot,
                                                 const float* __restrict__ xvh) {
    int idx = blockIdx.x * 256 + threadIdx.x;
    int n = idx >> 8, h = idx & 255;
    float xv1 = xvh[(long)n * 768 + h];
    float xv2 = xvh[(long)n * 768 + 256 + h];
    float xv3 = xvh[(long)n * 768 + 512 + h];
    x1[idx] = x1[idx] + (xv1 + xv2 * vdot[idx]) * INV_SQRT_2f;
    #pragma unroll
    for (int d = 0; d < 3; d++) {
        long r = (long)(n * 3 + d) * 256 + h;
        vecacc[r] = vecacc[r] + xv3 * vec1[r];
    }
}

// ---------------- norm over d + concat(x, norm) ----------------
__global__ void __launch_bounds__(256) normcat_kernel(const float* __restrict__ xin,
                                                      const float* __restrict__ w,
                                                      float* __restrict__ cat,
                                                      int Cx, int C, int shift) {
    int idx = blockIdx.x * 256 + threadIdx.x;
    int cols = 1 << shift;
    int n = idx >> shift, c = idx & (cols - 1);
    if (c < Cx) {
        cat[idx] = xin[(long)n * Cx + c];
    } else {
        int cc = c - Cx;
        float s = 0.f;
        #pragma unroll
        for (int d = 0; d < 3; d++) {
            float a = w[(long)(n * 3 + d) * C + cc];
            s += a * a;
        }
        cat[idx] = sqrtf(s);
    }
}

// ---------------- gated block 1 epilogue ----------------
__global__ void __launch_bounds__(256) gate1_kernel(const float* __restrict__ h1,
                                                    const float* __restrict__ w2,
                                                    float* __restrict__ x3,
                                                    float* __restrict__ vecC) {
    int idx = blockIdx.x * 256 + threadIdx.x;
    int n = idx >> 7, c = idx & 127;
    x3[idx] = ssilu_f(h1[(long)n * 256 + c]);
    float vn = h1[(long)n * 256 + 128 + c];
    #pragma unroll
    for (int d = 0; d < 3; d++) {
        long r = (long)(n * 3 + d);
        vecC[r * 128 + c] = vn * w2[r * 128 + c];
    }
}

// ---------------- vecC @ o2_Wv2 (K=128, Nc=1): one wave per row ----------------
__global__ void __launch_bounds__(256) g12_kernel(const float* __restrict__ vecC,
                                                  const float* __restrict__ Wv2,
                                                  float* __restrict__ w4) {
    int row = blockIdx.x * 4 + (threadIdx.x >> 6);
    int lane = threadIdx.x & 63;
    float s = vecC[(long)row * 128 + lane] * Wv2[lane] +
              vecC[(long)row * 128 + 64 + lane] * Wv2[64 + lane];
    #pragma unroll
    for (int off = 32; off > 0; off >>= 1) s += __shfl_down(s, off);
    if (lane == 0) w4[row] = s;
}

// ---------------- final: out[n,d] = (t5[n,:]@Wu2[:,1] + b2[1]) * w4[n,d] ----------
__global__ void __launch_bounds__(256) final_kernel(const float* __restrict__ t5,
                                                    const float* __restrict__ Wu2,
                                                    const float* __restrict__ bu2,
                                                    const float* __restrict__ w4,
                                                    float* __restrict__ out) {
    int n = blockIdx.x * 4 + (threadIdx.x >> 6);
    int lane = threadIdx.x & 63;
    float s = t5[(long)n * 128 + lane] * Wu2[lane * 2 + 1] +
              t5[(long)n * 128 + 64 + lane] * Wu2[(64 + lane) * 2 + 1];
    #pragma unroll
    for (int off = 32; off > 0; off >>= 1) s += __shfl_down(s, off);
    float val = __shfl(s, 0) + bu2[1];
    if (lane < 3) out[(long)n * 3 + lane] = val * w4[(long)n * 3 + lane];
}

extern "C" void kernel_launch(void* const* d_in, const int* in_sizes, int n_in,
                              void* d_out, int out_size, void* d_ws, size_t ws_size,
                              hipStream_t stream) {
    const float* x          = (const float*)d_in[0];
    const float* vec        = (const float*)d_in[1];
    const float* edge_rbf   = (const float*)d_in[2];
    const float* edge_vector= (const float*)d_in[3];
    const float* ln_g       = (const float*)d_in[4];
    const float* ln_b       = (const float*)d_in[5];
    const float* W_x1       = (const float*)d_in[6];
    const float* b_x1       = (const float*)d_in[7];
    const float* W_x2       = (const float*)d_in[8];
    const float* b_x2       = (const float*)d_in[9];
    const float* W_rbf      = (const float*)d_in[10];
    const float* b_rbf      = (const float*)d_in[11];
    const float* W_vp       = (const float*)d_in[12];
    const float* W_xv1      = (const float*)d_in[13];
    const float* b_xv1      = (const float*)d_in[14];
    const float* W_xv2      = (const float*)d_in[15];
    const float* b_xv2      = (const float*)d_in[16];
    const float* o1_Wv1     = (const float*)d_in[17];
    const float* o1_Wv2     = (const float*)d_in[18];
    const float* o1_Wu1     = (const float*)d_in[19];
    const float* o1_bu1     = (const float*)d_in[20];
    const float* o1_Wu2     = (const float*)d_in[21];
    const float* o1_bu2     = (const float*)d_in[22];
    const float* o2_Wv1     = (const float*)d_in[23];
    const float* o2_Wv2     = (const float*)d_in[24];
    const float* o2_Wu1     = (const float*)d_in[25];
    const float* o2_bu1     = (const float*)d_in[26];
    const float* o2_Wu2     = (const float*)d_in[27];
    const float* o2_bu2     = (const float*)d_in[28];
    const int*   edge_index = (const int*)d_in[29];
    float* out = (float*)d_out;
    float* ws  = (float*)d_ws;

    const size_t S = (size_t)NN * 256;   // 4,194,304 floats
    const size_t H_ = S / 2;             // half-S step for 128-col buffers
    // ---- arena: peak 13*S floats = 208 MiB ----
    // phase 1-3
    float* x1     = ws;              // [0,1)S   x+dx (in-place through e4)
    float* vecacc = ws + S;          // [1,4)S   vec+dvec (in-place through e4)
    float* xln    = ws + 4 * S;      // [4,5)S   dead after t1 gemm
    float* t1     = ws + 5 * S;      // [5,6)S   dead after xh gemm
    float* xh     = ws + 6 * S;      // [6,9)S   dead after edge_kernel
    float* vec1   = ws + 4 * S;      // [4,7)S   (xln/t1/xh dead)
    float* vec2   = ws + 7 * S;      // [7,10)S  dead after vdot_cat
    float* catb   = ws + 10 * S;     // [10,12)S dead after t2 gemm
    float* vdot   = ws + 12 * S;     // [12,13)S dead after e4
    float* t2     = ws + 7 * S;      // [7,8)S   (vec2 dead)
    float* xvh    = ws + 8 * S;      // [8,11)S  (vec2/catb dead) dead after e4
    // phase 4-5 (live after e4: x1 [0,1), vecacc [1,4))
    float* w1   = ws + 4 * S;            // [4,7)S    dead after normcat(cat2)
    float* w2   = ws + 7 * S;            // [7,8.5)S  dead after gate1
    float* cat2 = ws + 8 * S + H_;       // [8.5,10.5)S dead after t4 gemm
    float* t4   = ws + 4 * S;            // [4,5)S    (w1 dead)
    float* h1   = ws + 5 * S;            // [5,6)S    dead after gate1
    float* x3   = ws + 6 * S;            // [6,6.5)S  dead after normcat(cat3)
    float* vecC = ws + 8 * S + H_;       // [8.5,10)S (cat2 dead) dead after w3/w4
    float* w3   = ws + 4 * S;            // [4,5.5)S  (t4 dead) dead after normcat(cat3)
    float* w4   = ws + 6 * S + H_;       // [6.5,7)S  live to end (3N floats)
    float* cat3 = ws + 7 * S;            // [7,8)S    (w2 dead) dead after t5 gemm
    float* t5   = ws + 5 * S + H_;       // [5.5,6)S  (h1 dead by then)

    // Phase 1: node MLP
    ln_kernel<<<NN, 256, 0, stream>>>(x, ln_g, ln_b, xln);
    gemm_kernel<<<dim3(NN / 64, 4), 256, 0, stream>>>(xln, W_x1, b_x1, t1,
                                                      NN, 256, 256, 256, 256, 1);
    gemm_kernel<<<dim3(NN / 64, 12), 256, 0, stream>>>(t1, W_x2, b_x2, xh,
                                                       NN, 256, 768, 768, 768, 0);

    // Phase 2: edges (atomics accumulate on top of copies of x / vec)
    hipMemcpyAsync(x1, x, S * sizeof(float), hipMemcpyDeviceToDevice, stream);
    hipMemcpyAsync(vecacc, vec, 3 * S * sizeof(float), hipMemcpyDeviceToDevice, stream);
    edge_kernel<<<EE / EPB, 256, 0, stream>>>(edge_rbf, W_rbf, b_rbf, xh, vec,
                                              edge_vector, edge_index, x1, vecacc);

    // Phase 3: vp (split into vec1/vec2), vec_dot/vnorm, xv MLP, in-place updates
    gemm_kernel<<<dim3(3 * NN / 64, 4), 256, 0, stream>>>(vecacc, W_vp, nullptr, vec1,
                                                          3 * NN, 256, 256, 512, 256, 0);
    gemm_kernel<<<dim3(3 * NN / 64, 4), 256, 0, stream>>>(vecacc, W_vp + 256, nullptr, vec2,
                                                          3 * NN, 256, 256, 512, 256, 0);
    vdot_cat_kernel<<<NN, 256, 0, stream>>>(vec1, vec2, x1, vdot, catb);
    gemm_kernel<<<dim3(NN / 64, 4), 256, 0, stream>>>(catb, W_xv1, b_xv1, t2,
                                                      NN, 512, 256, 256, 256, 1);
    gemm_kernel<<<dim3(NN / 64, 12), 256, 0, stream>>>(t2, W_xv2, b_xv2, xvh,
                                                       NN, 256, 768, 768, 768, 0);
    e4_kernel<<<NN, 256, 0, stream>>>(x1, vecacc, vec1, vdot, xvh);

    // Phase 4: gated equivariant block 1 (x2 == x1, vecB == vecacc)
    gemm_kernel<<<dim3(3 * NN / 64, 4), 256, 0, stream>>>(vecacc, o1_Wv1, nullptr, w1,
                                                          3 * NN, 256, 256, 256, 256, 0);
    gemm_kernel<<<dim3(3 * NN / 64, 2), 256, 0, stream>>>(vecacc, o1_Wv2, nullptr, w2,
                                                          3 * NN, 256, 128, 128, 128, 0);
    normcat_kernel<<<NN * 512 / 256, 256, 0, stream>>>(x1, w1, cat2, 256, 256, 9);
    gemm_kernel<<<dim3(NN / 64, 4), 256, 0, stream>>>(cat2, o1_Wu1, o1_bu1, t4,
                                                      NN, 512, 256, 256, 256, 1);
    gemm_kernel<<<dim3(NN / 64, 4), 256, 0, stream>>>(t4, o1_Wu2, o1_bu2, h1,
                                                      NN, 256, 256, 256, 256, 0);
    gate1_kernel<<<NN * 128 / 256, 256, 0, stream>>>(h1, w2, x3, vecC);

    // Phase 5: gated equivariant block 2 + output
    gemm_kernel<<<dim3(3 * NN / 64, 2), 256, 0, stream>>>(vecC, o2_Wv1, nullptr, w3,
                                                          3 * NN, 128, 128, 128, 128, 0);
    g12_kernel<<<3 * NN / 4, 256, 0, stream>>>(vecC, o2_Wv2, w4);
    normcat_kernel<<<NN * 256 / 256, 256, 0, stream>>>(x3, w3, cat3, 128, 128, 8);
    gemm_kernel<<<dim3(NN / 64, 2), 256, 0, stream>>>(cat3, o2_Wu1, o2_bu1, t5,
                                                      NN, 256, 128, 128, 128, 1);
    final_kernel<<<NN / 4, 256, 0, stream>>>(t5, o2_Wu2, o2_bu2, w4, out);
}

// Round 3
// 1790.198 us; speedup vs baseline: 1.0908x; 1.0908x over previous
//
#include <hip/hip_runtime.h>
#include <math.h>

#define NN 16384
#define EE 262144
#define HH 256

#define INV_SQRT_3f 0.57735026918962576f
#define INV_SQRT_Hf 0.0625f
#define INV_SQRT_2f 0.70710678118654752f
#define SSILU_SCALE 1.6666666666666667f

__device__ __forceinline__ float ssilu_f(float v) {
    return v * (1.0f / (1.0f + __expf(-v))) * SSILU_SCALE;
}

// ---------------- LayerNorm: one block (256 thr) per row ----------------
__global__ void __launch_bounds__(256) ln_kernel(const float* __restrict__ x,
                                                 const float* __restrict__ g,
                                                 const float* __restrict__ b,
                                                 float* __restrict__ out) {
    int n = blockIdx.x;
    int t = threadIdx.x;
    float v = x[(long)n * HH + t];
    float s = v, s2 = v * v;
    #pragma unroll
    for (int off = 32; off > 0; off >>= 1) {
        s  += __shfl_down(s, off);
        s2 += __shfl_down(s2, off);
    }
    __shared__ float red[8];
    int wave = t >> 6, lane = t & 63;
    if (lane == 0) { red[wave] = s; red[4 + wave] = s2; }
    __syncthreads();
    __shared__ float mr[2];
    if (t == 0) {
        float ts = red[0] + red[1] + red[2] + red[3];
        float ts2 = red[4] + red[5] + red[6] + red[7];
        float mean = ts * (1.0f / HH);
        float var = ts2 * (1.0f / HH) - mean * mean;
        mr[0] = mean;
        mr[1] = rsqrtf(var + 1e-5f);
    }
    __syncthreads();
    out[(long)n * HH + t] = (v - mr[0]) * mr[1] * g[t] + b[t];
}

// ---- Generic tiled fp32 GEMM: C(M,Nc) = A(M,K) @ W(K,ldW sub-block) [+bias][ssilu]
__global__ void __launch_bounds__(256) gemm_kernel(const float* __restrict__ A,
                                                   const float* __restrict__ W,
                                                   const float* __restrict__ bias,
                                                   float* __restrict__ C,
                                                   int M, int K, int Nc,
                                                   int ldW, int ldC, int act) {
    __shared__ float As[16][68];
    __shared__ float Ws[16][64];
    int tid = threadIdx.x;
    int bm = blockIdx.x * 64;
    int bn = blockIdx.y * 64;
    int tx = tid & 15, ty = tid >> 4;
    int am = tid >> 2;
    int ak = (tid & 3) * 4;
    int wn = tid & 63, wk0 = tid >> 6;

    float acc[4][4];
    #pragma unroll
    for (int i = 0; i < 4; i++)
        #pragma unroll
        for (int j = 0; j < 4; j++) acc[i][j] = 0.0f;

    for (int k0 = 0; k0 < K; k0 += 16) {
        float4 av = *(const float4*)(A + (long)(bm + am) * K + k0 + ak);
        As[ak + 0][am] = av.x;
        As[ak + 1][am] = av.y;
        As[ak + 2][am] = av.z;
        As[ak + 3][am] = av.w;
        #pragma unroll
        for (int i = 0; i < 4; i++) {
            int k = i * 4 + wk0;
            Ws[k][wn] = W[(long)(k0 + k) * ldW + bn + wn];
        }
        __syncthreads();
        #pragma unroll
        for (int kk = 0; kk < 16; kk++) {
            float4 a4 = *(const float4*)(&As[kk][ty * 4]);
            float4 b4 = *(const float4*)(&Ws[kk][tx * 4]);
            float a[4] = {a4.x, a4.y, a4.z, a4.w};
            float b[4] = {b4.x, b4.y, b4.z, b4.w};
            #pragma unroll
            for (int i = 0; i < 4; i++)
                #pragma unroll
                for (int j = 0; j < 4; j++) acc[i][j] += a[i] * b[j];
        }
        __syncthreads();
    }

    float bj[4] = {0.f, 0.f, 0.f, 0.f};
    if (bias) {
        #pragma unroll
        for (int j = 0; j < 4; j++) bj[j] = bias[bn + tx * 4 + j];
    }
    #pragma unroll
    for (int i = 0; i < 4; i++) {
        long row = bm + ty * 4 + i;
        float v[4];
        #pragma unroll
        for (int j = 0; j < 4; j++) {
            v[j] = acc[i][j] + bj[j];
            if (act) v[j] = ssilu_f(v[j]);
        }
        float4 o = make_float4(v[0], v[1], v[2], v[3]);
        *(float4*)(C + row * ldC + bn + tx * 4) = o;
    }
}

// ---------------- edge sort (counting sort by dst) ----------------
__global__ void __launch_bounds__(256) zero_kernel(int* __restrict__ p, int n) {
    int i = blockIdx.x * 256 + threadIdx.x;
    if (i < n) p[i] = 0;
}

__global__ void __launch_bounds__(256) hist_kernel(const int* __restrict__ eidx,
                                                   int* __restrict__ cnt) {
    int e = blockIdx.x * 256 + threadIdx.x;
    atomicAdd(&cnt[eidx[EE + e]], 1);
}

// single block, 256 threads, 64 elems each: exclusive scan of cnt (=cursor array)
__global__ void __launch_bounds__(256) scan_kernel(int* __restrict__ cursor,
                                                   int* __restrict__ rowptr) {
    int t = threadIdx.x;
    int base_i = t * 64;
    int tsum = 0;
    for (int i = 0; i < 64; i++) tsum += cursor[base_i + i];
    __shared__ int ls[256];
    ls[t] = tsum;
    __syncthreads();
    for (int off = 1; off < 256; off <<= 1) {
        int v = (t >= off) ? ls[t - off] : 0;
        __syncthreads();
        ls[t] += v;
        __syncthreads();
    }
    int running = ls[t] - tsum;  // exclusive prefix
    for (int i = 0; i < 64; i++) {
        int c = cursor[base_i + i];
        rowptr[base_i + i] = running;
        cursor[base_i + i] = running;
        running += c;
    }
    if (t == 255) rowptr[NN] = running;
}

__global__ void __launch_bounds__(256) scatter_kernel(const int* __restrict__ eidx,
                                                      int* __restrict__ cursor,
                                                      int* __restrict__ perm) {
    int e = blockIdx.x * 256 + threadIdx.x;
    int d_ = eidx[EE + e];
    int pos = atomicAdd(&cursor[d_], 1);
    perm[pos] = e;
}

// ---------------- Node-gather edge kernel: CSR, no atomics ----------------
// One block per dst node; recompute rbfh in 16-edge batches; accumulate
// dx (1 reg) + dvec (3 regs) per thread; epilogue writes x+dx, vec+dvec.
#define EPB 16
__global__ void __launch_bounds__(256) node_gather_kernel(
        const float* __restrict__ rbf,
        const float* __restrict__ W_rbf,
        const float* __restrict__ b_rbf,
        const float* __restrict__ xh,
        const float* __restrict__ vec,
        const float* __restrict__ ev,
        const int* __restrict__ eidx,
        const float* __restrict__ x,
        const int* __restrict__ perm,
        const int* __restrict__ rowptr,
        float* __restrict__ x1,
        float* __restrict__ vecacc) {
    int n = blockIdx.x;
    int t = threadIdx.x;
    int beg = rowptr[n], deg = rowptr[n + 1] - beg;

    __shared__ float rbf_s[EPB][64];
    __shared__ int eid_s[EPB], src_s[EPB];
    __shared__ float ev_s[EPB][3];

    float bb1 = b_rbf[t], bb2 = b_rbf[256 + t], bb3 = b_rbf[512 + t];
    float dxa = 0.f, dv0 = 0.f, dv1 = 0.f, dv2 = 0.f;

    for (int b0 = 0; b0 < deg; b0 += EPB) {
        int cnt = min(EPB, deg - b0);
        __syncthreads();  // protect LDS from previous batch readers
        if (t < cnt) {
            int eid = perm[beg + b0 + t];
            eid_s[t] = eid;
            src_s[t] = eidx[eid];
        }
        __syncthreads();
        #pragma unroll
        for (int i = 0; i < (EPB * 64) / 256; i++) {
            int idx = i * 256 + t;
            int e = idx >> 6, k = idx & 63;
            rbf_s[e][k] = (e < cnt) ? rbf[(long)eid_s[e] * 64 + k] : 0.f;
        }
        if (t < cnt * 3) {
            int e = t / 3, d = t % 3;
            ev_s[e][d] = ev[(long)eid_s[e] * 3 + d];
        }
        __syncthreads();

        float acc1[EPB], acc2[EPB], acc3[EPB];
        #pragma unroll
        for (int e = 0; e < EPB; e++) { acc1[e] = bb1; acc2[e] = bb2; acc3[e] = bb3; }
        for (int k = 0; k < 64; k++) {
            float w1 = W_rbf[k * 768 + t];
            float w2 = W_rbf[k * 768 + 256 + t];
            float w3 = W_rbf[k * 768 + 512 + t];
            #pragma unroll
            for (int e = 0; e < EPB; e++) {
                float r = rbf_s[e][k];
                acc1[e] += r * w1;
                acc2[e] += r * w2;
                acc3[e] += r * w3;
            }
        }

        for (int e = 0; e < cnt; e++) {
            int s = src_s[e];
            const float* xr = xh + (long)s * 768;
            float m1 = acc1[e] * xr[t];
            float m2 = acc2[e] * xr[256 + t] * INV_SQRT_3f;
            float m3 = acc3[e] * xr[512 + t];
            const float* vr = vec + (long)s * 768;
            dxa += m1;
            dv0 += (vr[t] * m2 + m3 * ev_s[e][0]) * INV_SQRT_Hf;
            dv1 += (vr[256 + t] * m2 + m3 * ev_s[e][1]) * INV_SQRT_Hf;
            dv2 += (vr[512 + t] * m2 + m3 * ev_s[e][2]) * INV_SQRT_Hf;
        }
    }

    long nb = (long)n * 256 + t;
    x1[nb] = x[nb] + dxa;
    long vb = (long)n * 768 + t;
    vecacc[vb]       = vec[vb]       + dv0;
    vecacc[vb + 256] = vec[vb + 256] + dv1;
    vecacc[vb + 512] = vec[vb + 512] + dv2;
}

// ---------------- vec_dot + vnorm + cat(x, vnorm) ----------------
__global__ void __launch_bounds__(256) vdot_cat_kernel(const float* __restrict__ vec1,
                                                       const float* __restrict__ vec2,
                                                       const float* __restrict__ x1,
                                                       float* __restrict__ vdot,
                                                       float* __restrict__ cat) {
    int idx = blockIdx.x * 256 + threadIdx.x;
    int n = idx >> 8, h = idx & 255;
    float dsum = 0.f, s2 = 0.f;
    #pragma unroll
    for (int d = 0; d < 3; d++) {
        long r = (long)(n * 3 + d) * 256 + h;
        float a = vec1[r];
        float b = vec2[r];
        dsum += a * b;
        s2 += b * b;
    }
    vdot[idx] = dsum * INV_SQRT_Hf;
    cat[(long)n * 512 + h] = x1[idx];
    cat[(long)n * 512 + 256 + h] = sqrtf(s2 + 1e-8f);
}

// ---------------- x/vec update after xv MLP (IN-PLACE on x1 and vecacc) ----------
__global__ void __launch_bounds__(256) e4_kernel(float* __restrict__ x1,
                                                 float* __restrict__ vecacc,
                                                 const float* __restrict__ vec1,
                                                 const float* __restrict__ vdot,
                                                 const float* __restrict__ xvh) {
    int idx = blockIdx.x * 256 + threadIdx.x;
    int n = idx >> 8, h = idx & 255;
    float xv1 = xvh[(long)n * 768 + h];
    float xv2 = xvh[(long)n * 768 + 256 + h];
    float xv3 = xvh[(long)n * 768 + 512 + h];
    x1[idx] = x1[idx] + (xv1 + xv2 * vdot[idx]) * INV_SQRT_2f;
    #pragma unroll
    for (int d = 0; d < 3; d++) {
        long r = (long)(n * 3 + d) * 256 + h;
        vecacc[r] = vecacc[r] + xv3 * vec1[r];
    }
}

// ---------------- norm over d + concat(x, norm) ----------------
__global__ void __launch_bounds__(256) normcat_kernel(const float* __restrict__ xin,
                                                      const float* __restrict__ w,
                                                      float* __restrict__ cat,
                                                      int Cx, int C, int shift) {
    int idx = blockIdx.x * 256 + threadIdx.x;
    int cols = 1 << shift;
    int n = idx >> shift, c = idx & (cols - 1);
    if (c < Cx) {
        cat[idx] = xin[(long)n * Cx + c];
    } else {
        int cc = c - Cx;
        float s = 0.f;
        #pragma unroll
        for (int d = 0; d < 3; d++) {
            float a = w[(long)(n * 3 + d) * C + cc];
            s += a * a;
        }
        cat[idx] = sqrtf(s);
    }
}

// ---------------- gated block 1 epilogue ----------------
__global__ void __launch_bounds__(256) gate1_kernel(const float* __restrict__ h1,
                                                    const float* __restrict__ w2,
                                                    float* __restrict__ x3,
                                                    float* __restrict__ vecC) {
    int idx = blockIdx.x * 256 + threadIdx.x;
    int n = idx >> 7, c = idx & 127;
    x3[idx] = ssilu_f(h1[(long)n * 256 + c]);
    float vn = h1[(long)n * 256 + 128 + c];
    #pragma unroll
    for (int d = 0; d < 3; d++) {
        long r = (long)(n * 3 + d);
        vecC[r * 128 + c] = vn * w2[r * 128 + c];
    }
}

// ---------------- vecC @ o2_Wv2 (K=128, Nc=1): one wave per row ----------------
__global__ void __launch_bounds__(256) g12_kernel(const float* __restrict__ vecC,
                                                  const float* __restrict__ Wv2,
                                                  float* __restrict__ w4) {
    int row = blockIdx.x * 4 + (threadIdx.x >> 6);
    int lane = threadIdx.x & 63;
    float s = vecC[(long)row * 128 + lane] * Wv2[lane] +
              vecC[(long)row * 128 + 64 + lane] * Wv2[64 + lane];
    #pragma unroll
    for (int off = 32; off > 0; off >>= 1) s += __shfl_down(s, off);
    if (lane == 0) w4[row] = s;
}

// ---------------- final: out[n,d] = (t5[n,:]@Wu2[:,1] + b2[1]) * w4[n,d] ----------
__global__ void __launch_bounds__(256) final_kernel(const float* __restrict__ t5,
                                                    const float* __restrict__ Wu2,
                                                    const float* __restrict__ bu2,
                                                    const float* __restrict__ w4,
                                                    float* __restrict__ out) {
    int n = blockIdx.x * 4 + (threadIdx.x >> 6);
    int lane = threadIdx.x & 63;
    float s = t5[(long)n * 128 + lane] * Wu2[lane * 2 + 1] +
              t5[(long)n * 128 + 64 + lane] * Wu2[(64 + lane) * 2 + 1];
    #pragma unroll
    for (int off = 32; off > 0; off >>= 1) s += __shfl_down(s, off);
    float val = __shfl(s, 0) + bu2[1];
    if (lane < 3) out[(long)n * 3 + lane] = val * w4[(long)n * 3 + lane];
}

extern "C" void kernel_launch(void* const* d_in, const int* in_sizes, int n_in,
                              void* d_out, int out_size, void* d_ws, size_t ws_size,
                              hipStream_t stream) {
    const float* x          = (const float*)d_in[0];
    const float* vec        = (const float*)d_in[1];
    const float* edge_rbf   = (const float*)d_in[2];
    const float* edge_vector= (const float*)d_in[3];
    const float* ln_g       = (const float*)d_in[4];
    const float* ln_b       = (const float*)d_in[5];
    const float* W_x1       = (const float*)d_in[6];
    const float* b_x1       = (const float*)d_in[7];
    const float* W_x2       = (const float*)d_in[8];
    const float* b_x2       = (const float*)d_in[9];
    const float* W_rbf      = (const float*)d_in[10];
    const float* b_rbf      = (const float*)d_in[11];
    const float* W_vp       = (const float*)d_in[12];
    const float* W_xv1      = (const float*)d_in[13];
    const float* b_xv1      = (const float*)d_in[14];
    const float* W_xv2      = (const float*)d_in[15];
    const float* b_xv2      = (const float*)d_in[16];
    const float* o1_Wv1     = (const float*)d_in[17];
    const float* o1_Wv2     = (const float*)d_in[18];
    const float* o1_Wu1     = (const float*)d_in[19];
    const float* o1_bu1     = (const float*)d_in[20];
    const float* o1_Wu2     = (const float*)d_in[21];
    const float* o1_bu2     = (const float*)d_in[22];
    const float* o2_Wv1     = (const float*)d_in[23];
    const float* o2_Wv2     = (const float*)d_in[24];
    const float* o2_Wu1     = (const float*)d_in[25];
    const float* o2_bu1     = (const float*)d_in[26];
    const float* o2_Wu2     = (const float*)d_in[27];
    const float* o2_bu2     = (const float*)d_in[28];
    const int*   edge_index = (const int*)d_in[29];
    float* out = (float*)d_out;
    float* ws  = (float*)d_ws;

    const size_t S = (size_t)NN * 256;   // 4,194,304 floats
    const size_t H_ = S / 2;
    // ---- arena: peak 13*S floats = 208 MiB ----
    float* x1     = ws;              // [0,1)S
    float* vecacc = ws + S;          // [1,4)S
    float* xln    = ws + 4 * S;      // [4,5)S
    float* t1     = ws + 5 * S;      // [5,6)S
    float* xh     = ws + 6 * S;      // [6,9)S  dead after node_gather
    // edge-sort scratch lives in [9,10)S during the edge phase (vec2 written later)
    int* rowptr = (int*)(ws + 9 * S);          // 16385 ints
    int* cursor = rowptr + (NN + 1);           // 16384 ints (hist counts -> offsets)
    int* perm   = cursor + NN;                 // EE ints
    float* vec1   = ws + 4 * S;      // [4,7)S
    float* vec2   = ws + 7 * S;      // [7,10)S
    float* catb   = ws + 10 * S;     // [10,12)S
    float* vdot   = ws + 12 * S;     // [12,13)S
    float* t2     = ws + 7 * S;      // [7,8)S
    float* xvh    = ws + 8 * S;      // [8,11)S
    float* w1   = ws + 4 * S;            // [4,7)S
    float* w2   = ws + 7 * S;            // [7,8.5)S
    float* cat2 = ws + 8 * S + H_;       // [8.5,10.5)S
    float* t4   = ws + 4 * S;            // [4,5)S
    float* h1   = ws + 5 * S;            // [5,6)S
    float* x3   = ws + 6 * S;            // [6,6.5)S
    float* vecC = ws + 8 * S + H_;       // [8.5,10)S
    float* w3   = ws + 4 * S;            // [4,5.5)S
    float* w4   = ws + 6 * S + H_;       // [6.5,7)S
    float* cat3 = ws + 7 * S;            // [7,8)S
    float* t5   = ws + 5 * S + H_;       // [5.5,6)S

    // Phase 1: node MLP
    ln_kernel<<<NN, 256, 0, stream>>>(x, ln_g, ln_b, xln);
    gemm_kernel<<<dim3(NN / 64, 4), 256, 0, stream>>>(xln, W_x1, b_x1, t1,
                                                      NN, 256, 256, 256, 256, 1);
    gemm_kernel<<<dim3(NN / 64, 12), 256, 0, stream>>>(t1, W_x2, b_x2, xh,
                                                       NN, 256, 768, 768, 768, 0);

    // Phase 2: counting-sort edges by dst, then CSR node-gather (no atomics)
    zero_kernel<<<NN / 256, 256, 0, stream>>>(cursor, NN);
    hist_kernel<<<EE / 256, 256, 0, stream>>>(edge_index, cursor);
    scan_kernel<<<1, 256, 0, stream>>>(cursor, rowptr);
    scatter_kernel<<<EE / 256, 256, 0, stream>>>(edge_index, cursor, perm);
    node_gather_kernel<<<NN, 256, 0, stream>>>(edge_rbf, W_rbf, b_rbf, xh, vec,
                                               edge_vector, edge_index, x,
                                               perm, rowptr, x1, vecacc);

    // Phase 3: vp (split into vec1/vec2), vec_dot/vnorm, xv MLP, in-place updates
    gemm_kernel<<<dim3(3 * NN / 64, 4), 256, 0, stream>>>(vecacc, W_vp, nullptr, vec1,
                                                          3 * NN, 256, 256, 512, 256, 0);
    gemm_kernel<<<dim3(3 * NN / 64, 4), 256, 0, stream>>>(vecacc, W_vp + 256, nullptr, vec2,
                                                          3 * NN, 256, 256, 512, 256, 0);
    vdot_cat_kernel<<<NN, 256, 0, stream>>>(vec1, vec2, x1, vdot, catb);
    gemm_kernel<<<dim3(NN / 64, 4), 256, 0, stream>>>(catb, W_xv1, b_xv1, t2,
                                                      NN, 512, 256, 256, 256, 1);
    gemm_kernel<<<dim3(NN / 64, 12), 256, 0, stream>>>(t2, W_xv2, b_xv2, xvh,
                                                       NN, 256, 768, 768, 768, 0);
    e4_kernel<<<NN, 256, 0, stream>>>(x1, vecacc, vec1, vdot, xvh);

    // Phase 4: gated equivariant block 1
    gemm_kernel<<<dim3(3 * NN / 64, 4), 256, 0, stream>>>(vecacc, o1_Wv1, nullptr, w1,
                                                          3 * NN, 256, 256, 256, 256, 0);
    gemm_kernel<<<dim3(3 * NN / 64, 2), 256, 0, stream>>>(vecacc, o1_Wv2, nullptr, w2,
                                                          3 * NN, 256, 128, 128, 128, 0);
    normcat_kernel<<<NN * 512 / 256, 256, 0, stream>>>(x1, w1, cat2, 256, 256, 9);
    gemm_kernel<<<dim3(NN / 64, 4), 256, 0, stream>>>(cat2, o1_Wu1, o1_bu1, t4,
                                                      NN, 512, 256, 256, 256, 1);
    gemm_kernel<<<dim3(NN / 64, 4), 256, 0, stream>>>(t4, o1_Wu2, o1_bu2, h1,
                                                      NN, 256, 256, 256, 256, 0);
    gate1_kernel<<<NN * 128 / 256, 256, 0, stream>>>(h1, w2, x3, vecC);

    // Phase 5: gated equivariant block 2 + output
    gemm_kernel<<<dim3(3 * NN / 64, 2), 256, 0, stream>>>(vecC, o2_Wv1, nullptr, w3,
                                                          3 * NN, 128, 128, 128, 128, 0);
    g12_kernel<<<3 * NN / 4, 256, 0, stream>>>(vecC, o2_Wv2, w4);
    normcat_kernel<<<NN * 256 / 256, 256, 0, stream>>>(x3, w3, cat3, 128, 128, 8);
    gemm_kernel<<<dim3(NN / 64, 2), 256, 0, stream>>>(cat3, o2_Wu1, o2_bu1, t5,
                                                      NN, 256, 128, 128, 128, 1);
    final_kernel<<<NN / 4, 256, 0, stream>>>(t5, o2_Wu2, o2_bu2, w4, out);
}